// Round 15
// baseline (159.678 us; speedup 1.0000x reference)
//
#include <hip/hip_runtime.h>
#include <hip/hip_bf16.h>

#define VOCAB  200000
#define NTILES 12800            // 204800 rows / 16
#define GRID   1280             // blocks; ~3 resident/CU (LDS 49.8 KB)
#define ITERS  10               // NTILES / GRID
#define DEPTH  3                // LDS A-buffer ring (2 tiles prefetch ahead)

typedef __attribute__((ext_vector_type(4))) float  f32x4;
typedef __attribute__((ext_vector_type(4))) int    i32x4;
typedef __attribute__((ext_vector_type(8))) __bf16 bf16x8;

typedef const __attribute__((address_space(1))) unsigned int* gas_u32p;
typedef __attribute__((address_space(3))) unsigned int* las_u32p;

__device__ __forceinline__ __bf16 f2bf(float f) {
    unsigned u = __builtin_bit_cast(unsigned, f);
    u += 0x7FFFu + ((u >> 16) & 1u);           // round-to-nearest-even
    unsigned short s = (unsigned short)(u >> 16);
    return __builtin_bit_cast(__bf16, s);
}

// Pack B into MFMA fragment order (verified round 1).
// k = a*16 + b;  B[k][j] = core1[b, j, a], core1 is (16,256,16).
// bpk[(kk*16 + nt)*64 + lane] : lane l elem e = B[kk*32 + (l>>4)*8 + e][nt*16 + (l&15)]
__global__ void pack_b_kernel(const float* __restrict__ core1, bf16x8* __restrict__ bpk) {
    int t    = blockIdx.x * 256 + threadIdx.x;   // 0..8191
    int lane = t & 63;
    int nt   = (t >> 6) & 15;
    int kk   = t >> 10;
    int j     = nt * 16 + (lane & 15);
    int kbase = kk * 32 + ((lane >> 4) * 8);
    bf16x8 v;
#pragma unroll
    for (int e = 0; e < 8; ++e) {
        int k = kbase + e;
        int b = k & 15, a = k >> 4;
        v[e] = f2bf(core1[(b * 256 + j) * 16 + a]);
    }
    bpk[t] = v;
}

// A-gather for k-slab kk of a 16-row tile into LDS buffer abuf (zero VGPR,
// proven r9). Lane l fetches chunk c = kk*8 + (l>>4)*2 + h of row idx_{l&15};
// chunk c = floats 4c..4c+3 (k = a*16+b: a = c>>2, b = (c&3)*4..+3). Per row
// this reads two 64B-aligned full lines (rows are 64B-aligned).
// LDS image: kk*2048 + h*1024 + lane*16 -> compute ds_read_b128 contiguous.
__device__ __forceinline__ void issue_gather(const float* __restrict__ core0, int idx,
                                             int kk, char* abuf, int lane) {
    const int q = lane >> 4;
#pragma unroll
    for (int h = 0; h < 2; ++h) {
        int c = kk * 8 + q * 2 + h;
        const float* src = core0 + ((long)(c >> 2) * VOCAB + idx) * 16 + (c & 3) * 4;
        __builtin_amdgcn_global_load_lds((gas_u32p)src,
                                         (las_u32p)(abuf + kk * 2048 + h * 1024), 16, 0, 0);
    }
}

// r9 skeleton, occupancy-raised: DEPTH=3 ring (proven r13), direct C stores
// (proven r9, C-LDS funnel was neutral in r13), LDS 49.8 KB -> 3 blocks/CU
// (launch_bounds(512,6) = 24 waves/CU target). Grid 1280 x 10 iters.
// vmcnt(16): ops newer than g(i+1) at the wait = st(i-1)[8] + g(i+2)[2] +
// st(i)[8] = 18 steady, 16 in tail (no g issued) -> vmcnt(16) retires g(i+1)
// in both; barrier then publishes every wave's tile-(i+1) slab.
__global__ __launch_bounds__(512, 6) void tr_embed_kernel(
        const int* __restrict__ x, const float* __restrict__ core0,
        const bf16x8* __restrict__ bpk, float* __restrict__ out) {
    __shared__ char lds[DEPTH * 16384 + ITERS * 16 * 4];   // A-ring | idx (49.8 KB)
    char* const ldsA = lds;
    int*  const sIdx = (int*)(lds + DEPTH * 16384);
    const int tid  = threadIdx.x;
    const int lane = tid & 63;
    const int wave = tid >> 6;                  // 0..7
    const int r    = lane & 15;
    const int q    = lane >> 4;

    // B panel -> registers: wave w owns nt = 2w, 2w+1 (proven r9)
    bf16x8 B0[8], B1[8];
#pragma unroll
    for (int kk = 0; kk < 8; ++kk) {
        B0[kk] = bpk[(kk * 16 + 2 * wave)     * 64 + lane];
        B1[kk] = bpk[(kk * 16 + 2 * wave + 1) * 64 + lane];
    }

    const int b0 = blockIdx.x;

    // stage all idx values into LDS (off the vmcnt path; proven r9)
    for (int j = tid; j < ITERS * 16; j += 512)
        sIdx[j] = x[(b0 + (j >> 4) * GRID) * 16 + (j & 15)];
    __syncthreads();

    // prologue: gather tiles 0,1 into ring slots 0,1; full drain
#pragma unroll
    for (int p = 0; p < 2; ++p)
        issue_gather(core0, sIdx[p * 16 + r], wave, ldsA + p * 16384, lane);
    asm volatile("s_waitcnt vmcnt(0)" ::: "memory");
    __builtin_amdgcn_s_barrier();
    __builtin_amdgcn_sched_barrier(0);

    int slot = 0;
    for (int i = 0; i < ITERS; ++i) {
        const int t = b0 + i * GRID;
        char* cur = ldsA + slot * 16384;

        // issue gathers for tile i+2 into ring slot (slot+2)%3
        if (i + 2 < ITERS) {
            int ns = slot + 2; if (ns >= DEPTH) ns -= DEPTH;
            issue_gather(core0, sIdx[(i + 2) * 16 + r], wave, ldsA + ns * 16384, lane);
        }
        __builtin_amdgcn_sched_barrier(0);      // pin gather issue at iter top

        // ---- compute 16 rows x 32 cols per wave (LDS A + reg B) ----
        f32x4 acc0 = {}, acc1 = {};
#pragma unroll
        for (int kk = 0; kk < 8; ++kk) {
            f32x4 lo = *(const f32x4*)(cur + kk * 2048 +        lane * 16);
            f32x4 hi = *(const f32x4*)(cur + kk * 2048 + 1024 + lane * 16);
            int p0, p1, p2, p3;                 // RNE packed f32->bf16
            asm("v_cvt_pk_bf16_f32 %0, %1, %2" : "=v"(p0) : "v"(lo[0]), "v"(lo[1]));
            asm("v_cvt_pk_bf16_f32 %0, %1, %2" : "=v"(p1) : "v"(lo[2]), "v"(lo[3]));
            asm("v_cvt_pk_bf16_f32 %0, %1, %2" : "=v"(p2) : "v"(hi[0]), "v"(hi[1]));
            asm("v_cvt_pk_bf16_f32 %0, %1, %2" : "=v"(p3) : "v"(hi[2]), "v"(hi[3]));
            i32x4 pk = { p0, p1, p2, p3 };
            bf16x8 af = __builtin_bit_cast(bf16x8, pk);
            acc0 = __builtin_amdgcn_mfma_f32_16x16x32_bf16(af, B0[kk], acc0, 0, 0, 0);
            acc1 = __builtin_amdgcn_mfma_f32_16x16x32_bf16(af, B1[kk], acc1, 0, 0, 0);
        }

        // ---- direct C stores (proven r9): col = lane&15, row = q*4 + e ----
        float* ob = out + (long)t * 16 * 256 + (q * 4) * 256 + 2 * wave * 16 + r;
#pragma unroll
        for (int e = 0; e < 4; ++e) {
            ob[e * 256]      = acc0[e];
            ob[e * 256 + 16] = acc1[e];
        }

        // counted drain (see header comment) + barrier
        asm volatile("s_waitcnt vmcnt(16)" ::: "memory");
        __builtin_amdgcn_s_barrier();
        __builtin_amdgcn_sched_barrier(0);

        slot = (slot == DEPTH - 1) ? 0 : slot + 1;
    }
}

extern "C" void kernel_launch(void* const* d_in, const int* in_sizes, int n_in,
                              void* d_out, int out_size, void* d_ws, size_t ws_size,
                              hipStream_t stream) {
    const int*   x     = (const int*)d_in[0];
    const float* core0 = (const float*)d_in[1];
    const float* core1 = (const float*)d_in[2];
    float* out = (float*)d_out;
    bf16x8* bpk = (bf16x8*)d_ws;                // 128 KB scratch

    pack_b_kernel<<<32, 256, 0, stream>>>(core1, bpk);
    tr_embed_kernel<<<GRID, 512, 0, stream>>>(x, core0, bpk, out);
}

// Round 16
// 108.353 us; speedup vs baseline: 1.4737x; 1.4737x over previous
//
#include <hip/hip_runtime.h>
#include <hip/hip_bf16.h>

#define VOCAB  200000
#define NTILES 12800            // 204800 rows / 16
#define GRID   512              // persistent blocks; grid caps residency at 2/CU
#define ITERS  25               // NTILES / GRID
#define DEPTH  3                // LDS A-buffer ring (2 tiles prefetch ahead)

typedef __attribute__((ext_vector_type(4))) float  f32x4;
typedef __attribute__((ext_vector_type(4))) int    i32x4;
typedef __attribute__((ext_vector_type(8))) __bf16 bf16x8;

typedef const __attribute__((address_space(1))) unsigned int* gas_u32p;
typedef __attribute__((address_space(3))) unsigned int* las_u32p;

__device__ __forceinline__ __bf16 f2bf(float f) {
    unsigned u = __builtin_bit_cast(unsigned, f);
    u += 0x7FFFu + ((u >> 16) & 1u);           // round-to-nearest-even
    unsigned short s = (unsigned short)(u >> 16);
    return __builtin_bit_cast(__bf16, s);
}

// Pack B into MFMA fragment order (verified round 1).
// k = a*16 + b;  B[k][j] = core1[b, j, a], core1 is (16,256,16).
// bpk[(kk*16 + nt)*64 + lane] : lane l elem e = B[kk*32 + (l>>4)*8 + e][nt*16 + (l&15)]
__global__ void pack_b_kernel(const float* __restrict__ core1, bf16x8* __restrict__ bpk) {
    int t    = blockIdx.x * 256 + threadIdx.x;   // 0..8191
    int lane = t & 63;
    int nt   = (t >> 6) & 15;
    int kk   = t >> 10;
    int j     = nt * 16 + (lane & 15);
    int kbase = kk * 32 + ((lane >> 4) * 8);
    bf16x8 v;
#pragma unroll
    for (int e = 0; e < 8; ++e) {
        int k = kbase + e;
        int b = k & 15, a = k >> 4;
        v[e] = f2bf(core1[(b * 256 + j) * 16 + a]);
    }
    bpk[t] = v;
}

// A-gather, FULL-LINE COALESCED remap. Inst (kk, h): lane l = q*16+r fetches
// chunk c = kk*8 + h*4 + q of row idx_r = core0[plane 2kk+h][idx_r][q*4..q*4+3]
// -> per row the 4 q-lanes read ONE contiguous 64 B line (one L2 transaction;
// the old map split every line across 2 insts x 2 pieces = 4 transactions).
// LDS image: abuf + kk*2048 + h*1024 + q*256 + r*16 (HW: base + lane*16).
__device__ __forceinline__ void issue_gather(const float* __restrict__ core0, int idx,
                                             int kk, char* abuf, int lane) {
    const int q = lane >> 4;
#pragma unroll
    for (int h = 0; h < 2; ++h) {
        const float* src = core0 + ((long)(2 * kk + h) * VOCAB + idx) * 16 + q * 4;
        __builtin_amdgcn_global_load_lds((gas_u32p)src,
                                         (las_u32p)(abuf + kk * 2048 + h * 1024), 16, 0, 0);
    }
}

// r9/r13/r15-proven skeleton: B panel in regs, 3-deep LDS A-ring filled by
// zero-VGPR global_load_lds, sIdx staged in LDS, direct C stores, counted
// vmcnt(16) + raw barrier per iter (ops newer than g(i+1) at the wait =
// st(i-1)[8] + g(i+2)[2] + st(i)[8] = 18 steady / 16 tail; r15-validated).
// A-fragment read (re-derived for the remap): lane (q,r), slab kk:
//   af[0..3] = chunk kk*8+2q  -> LDS kk*2048 + (q>>1)*1024 + ((2q)&3)*256 + r*16
//            = kk*2048 + q*512 + r*16;  af[4..7] at +256.  (checked q=0..3)
__global__ __launch_bounds__(512, 4) void tr_embed_kernel(
        const int* __restrict__ x, const float* __restrict__ core0,
        const bf16x8* __restrict__ bpk, float* __restrict__ out) {
    __shared__ char lds[DEPTH * 16384 + ITERS * 16 * 4];   // A-ring | idx
    char* const ldsA = lds;
    int*  const sIdx = (int*)(lds + DEPTH * 16384);
    const int tid  = threadIdx.x;
    const int lane = tid & 63;
    const int wave = tid >> 6;                  // 0..7
    const int r    = lane & 15;
    const int q    = lane >> 4;
    const int laneOff = q * 512 + r * 16;       // A-fragment LDS offset (remap)

    // B panel -> registers: wave w owns nt = 2w, 2w+1 (proven r9)
    bf16x8 B0[8], B1[8];
#pragma unroll
    for (int kk = 0; kk < 8; ++kk) {
        B0[kk] = bpk[(kk * 16 + 2 * wave)     * 64 + lane];
        B1[kk] = bpk[(kk * 16 + 2 * wave + 1) * 64 + lane];
    }

    const int b0 = blockIdx.x;

    // stage all idx values into LDS (off the vmcnt path; proven r9)
    for (int j = tid; j < ITERS * 16; j += 512)
        sIdx[j] = x[(b0 + (j >> 4) * GRID) * 16 + (j & 15)];
    __syncthreads();

    // prologue: gather tiles 0,1 into ring slots 0,1; full drain
#pragma unroll
    for (int p = 0; p < 2; ++p)
        issue_gather(core0, sIdx[p * 16 + r], wave, ldsA + p * 16384, lane);
    asm volatile("s_waitcnt vmcnt(0)" ::: "memory");
    __builtin_amdgcn_s_barrier();
    __builtin_amdgcn_sched_barrier(0);

    int slot = 0;
    for (int i = 0; i < ITERS; ++i) {
        const int t = b0 + i * GRID;
        char* cur = ldsA + slot * 16384;

        // issue gathers for tile i+2 into ring slot (slot+2)%3
        if (i + 2 < ITERS) {
            int ns = slot + 2; if (ns >= DEPTH) ns -= DEPTH;
            issue_gather(core0, sIdx[(i + 2) * 16 + r], wave, ldsA + ns * 16384, lane);
        }
        __builtin_amdgcn_sched_barrier(0);      // pin gather issue at iter top

        // ---- compute 16 rows x 32 cols per wave (LDS A + reg B) ----
        f32x4 acc0 = {}, acc1 = {};
#pragma unroll
        for (int kk = 0; kk < 8; ++kk) {
            f32x4 lo = *(const f32x4*)(cur + kk * 2048 + laneOff);
            f32x4 hi = *(const f32x4*)(cur + kk * 2048 + laneOff + 256);
            int p0, p1, p2, p3;                 // RNE packed f32->bf16
            asm("v_cvt_pk_bf16_f32 %0, %1, %2" : "=v"(p0) : "v"(lo[0]), "v"(lo[1]));
            asm("v_cvt_pk_bf16_f32 %0, %1, %2" : "=v"(p1) : "v"(lo[2]), "v"(lo[3]));
            asm("v_cvt_pk_bf16_f32 %0, %1, %2" : "=v"(p2) : "v"(hi[0]), "v"(hi[1]));
            asm("v_cvt_pk_bf16_f32 %0, %1, %2" : "=v"(p3) : "v"(hi[2]), "v"(hi[3]));
            i32x4 pk = { p0, p1, p2, p3 };
            bf16x8 af = __builtin_bit_cast(bf16x8, pk);
            acc0 = __builtin_amdgcn_mfma_f32_16x16x32_bf16(af, B0[kk], acc0, 0, 0, 0);
            acc1 = __builtin_amdgcn_mfma_f32_16x16x32_bf16(af, B1[kk], acc1, 0, 0, 0);
        }

        // ---- direct C stores (proven r9): col = lane&15, row = q*4 + e ----
        float* ob = out + (long)t * 16 * 256 + (q * 4) * 256 + 2 * wave * 16 + r;
#pragma unroll
        for (int e = 0; e < 4; ++e) {
            ob[e * 256]      = acc0[e];
            ob[e * 256 + 16] = acc1[e];
        }

        // counted drain (r15-validated math) + barrier
        asm volatile("s_waitcnt vmcnt(16)" ::: "memory");
        __builtin_amdgcn_s_barrier();
        __builtin_amdgcn_sched_barrier(0);

        slot = (slot == DEPTH - 1) ? 0 : slot + 1;
    }
}

extern "C" void kernel_launch(void* const* d_in, const int* in_sizes, int n_in,
                              void* d_out, int out_size, void* d_ws, size_t ws_size,
                              hipStream_t stream) {
    const int*   x     = (const int*)d_in[0];
    const float* core0 = (const float*)d_in[1];
    const float* core1 = (const float*)d_in[2];
    float* out = (float*)d_out;
    bf16x8* bpk = (bf16x8*)d_ws;                // 128 KB scratch

    pack_b_kernel<<<32, 256, 0, stream>>>(core1, bpk);
    tr_embed_kernel<<<GRID, 512, 0, stream>>>(x, core0, bpk, out);
}